// Round 16
// baseline (207.788 us; speedup 1.0000x reference)
//
#include <hip/hip_runtime.h>
#include <math.h>

#define BB 8
#define CC 128
#define CH 64
#define HH 160
#define WW 160
#define HW (HH*WW)
#define PP 162            // padded width/height for conv2 input
#define INF __builtin_inff()

typedef __bf16 bfv8 __attribute__((ext_vector_type(8)));
typedef __bf16 bfv4 __attribute__((ext_vector_type(4)));
typedef float  f4   __attribute__((ext_vector_type(4)));

__device__ __forceinline__ float sgm(float z){ return 1.0f/(1.0f + __expf(-z)); }
__device__ __forceinline__ float silu_(float z){ return z/(1.0f + __expf(-z)); }
__device__ __forceinline__ f4 MFMA(bfv8 a, bfv8 b, f4 c){
  return __builtin_amdgcn_mfma_f32_16x16x32_bf16(a, b, c, 0, 0, 0);
}

// clipped 3-point horizontal max/min at column w of row r (xs rows)
__device__ __forceinline__ float hrow3L(const float* __restrict__ r, int w,
                                        float& hM, float& hm){
  float cv = r[w];
  float M = cv, m = cv;
  if(w > 0){ float l = r[w-1]; M = fmaxf(M,l); m = fminf(m,l); }
  if(w < WW-1){ float rr = r[w+1]; M = fmaxf(M,rr); m = fminf(m,rr); }
  hM = M; hm = m; return cv;
}

// KPREP2: blocks 0-63 = weight prep; blocks 64-71 = border zero
__global__ __launch_bounds__(256) void kprep2(const float* __restrict__ w1,
                                              const float* __restrict__ g1, const float* __restrict__ b1,
                                              const float* __restrict__ m1, const float* __restrict__ v1,
                                              const float* __restrict__ w2,
                                              const float* __restrict__ g2, const float* __restrict__ b2,
                                              const float* __restrict__ m2, const float* __restrict__ v2,
                                              const float* __restrict__ w3,
                                              const float* __restrict__ g3, const float* __restrict__ b3,
                                              const float* __restrict__ m3, const float* __restrict__ v3,
                                              __bf16* __restrict__ w1b, __bf16* __restrict__ w2b,
                                              __bf16* __restrict__ w3b, float* __restrict__ scsh,
                                              __bf16* __restrict__ o1p){
  int bid = blockIdx.x;
  if(bid < 64){
    int t = bid*256 + threadIdx.x;
    int stride = 64*256;
    for(int i=t; i<CH*CC; i+=stride) w1b[i] = (__bf16)w1[i];
    for(int i=t; i<CC*CH; i+=stride) w3b[i] = (__bf16)w3[i];
    for(int i=t; i<9*CH*CH; i+=stride){
      int tap = i >> 12; int rem = i & 4095; int oc = rem >> 6; int ic = rem & 63;
      w2b[i] = (__bf16)w2[(oc*CH + ic)*9 + tap];
    }
    if(t < CH){
      float s = g1[t]*rsqrtf(v1[t] + 1e-5f);
      scsh[t] = s; scsh[64+t] = b1[t] - m1[t]*s;
      float s2 = g2[t]*rsqrtf(v2[t] + 1e-5f);
      scsh[128+t] = s2; scsh[192+t] = b2[t] - m2[t]*s2;
    }
    if(t >= 64 && t < 64+CC){
      int c = t - 64;
      float s3 = g3[c]*rsqrtf(v3[c] + 1e-5f);
      scsh[256+c] = s3; scsh[384+c] = b3[c] - m3[c]*s3;
    }
  } else {
    int b = bid - 64;
    __bf16* base = o1p + (size_t)b*PP*PP*CH;
    int t = threadIdx.x;
    bfv4 z = {(__bf16)0.f,(__bf16)0.f,(__bf16)0.f,(__bf16)0.f};
    for(int i=t; i<644*16; i+=256){
      int e = i >> 4; int c4 = (i & 15)*4;
      int h, w;
      if(e < 162){ h = 0; w = e; }
      else if(e < 324){ h = 161; w = e - 162; }
      else if(e < 484){ h = e - 324 + 1; w = 0; }
      else { h = e - 484 + 1; w = 161; }
      *(bfv4*)(base + ((size_t)h*PP + w)*CH + c4) = z;
    }
  }
}

// ---- k12 helpers: single C stream, halo via intra-wave shuffle ----
__device__ __forceinline__ void load8s(const float* __restrict__ xp, int lc,
                                       int start, float (&C)[8]){
  #pragma unroll
  for(int k=0;k<8;++k){
    int hr = start + k;
    C[k] = (hr < HH) ? xp[hr*WW + lc] : 0.f;
  }
}

__device__ __forceinline__ void proc1s(int base, const float (&C)[8],
                                       float& Mp, float& mp, float& Mc, float& mc,
                                       float& mn, float& sum){
  #pragma unroll
  for(int k=0;k<8;++k){
    int hr = base + 1 + k;
    float Lv = __shfl_up(C[k],1), Rv = __shfl_down(C[k],1);
    float Mn, mr;
    if(hr < HH){
      Mn = fmaxf(fmaxf(Lv,C[k]),Rv);
      mr = fminf(fminf(Lv,C[k]),Rv);
      mn = fminf(mn, C[k]);
    } else { Mn = -INF; mr = INF; }
    sum += fmaxf(fmaxf(Mp,Mc),Mn) - fminf(fminf(mp,mc),mr);
    Mp=Mc; mp=mc; Mc=Mn; mc=mr;
  }
}

__device__ __forceinline__ void proc2s(int base, int lc, bool act, const float (&C)[8],
                                       float& Mp, float& mp, float& Mc, float& mc,
                                       float& cen, float& amax, float& asum,
                                       float th, float basev, float s,
                                       __bf16* __restrict__ fp){
  #pragma unroll
  for(int k=0;k<8;++k){
    int hr = base + 1 + k;
    int h  = base + k;
    float Lv = __shfl_up(C[k],1), Rv = __shfl_down(C[k],1);
    float Mn, mr;
    if(hr < HH){
      Mn = fmaxf(fmaxf(Lv,C[k]),Rv);
      mr = fminf(fminf(Lv,C[k]),Rv);
    } else { Mn = -INF; mr = INF; }
    float contrast = fmaxf(fmaxf(Mp,Mc),Mn) - fminf(fminf(mp,mc),mr);
    float f = (contrast < th) ? cen*(1.f-s) + basev*s : cen;
    if(act) fp[h*WW + lc] = (__bf16)f;
    float a = fabsf(f);
    amax = fmaxf(amax, a); asum += a;
    Mp=Mc; mp=mc; Mc=Mn; mc=mr; cen = C[k];
  }
}

// K12: R14 passing version, unchanged (frozen).
__global__ __launch_bounds__(192) void k12(const float* __restrict__ x,
                                           const float* __restrict__ fsr,
                                           __bf16* __restrict__ fill16,
                                           float* __restrict__ chw){
  __shared__ float ra[256], rb[256];
  __shared__ float sb[2];
  int bc = blockIdx.x;
  int c  = bc & (CC-1);
  int t  = threadIdx.x;
  int w  = t >> 6, l = t & 63;
  int oc = 62*w + l - 1;
  bool act = (l >= 1) && (l <= 62) && (oc < WW);
  int lc = oc < 0 ? 0 : (oc > WW-1 ? WW-1 : oc);
  const float* xp = x + (size_t)bc*HW;

  float CA[8], CB[8];

  float mn = INF, sum = 0.f;
  float Mp=-INF, mp=INF, Mc, mc;
  {
    float C0 = xp[lc];
    float Lv = __shfl_up(C0,1), Rv = __shfl_down(C0,1);
    Mc = fmaxf(fmaxf(Lv,C0),Rv); mc = fminf(fminf(Lv,C0),Rv);
    mn = C0;
  }
  load8s(xp, lc, 1, CA);
  for(int h0=0; h0<HH; h0+=16){
    load8s(xp, lc, h0+9, CB);
    proc1s(h0,   CA, Mp, mp, Mc, mc, mn, sum);
    if(h0+16 < HH) load8s(xp, lc, h0+17, CA);
    proc1s(h0+8, CB, Mp, mp, Mc, mc, mn, sum);
  }
  ra[t] = act ? mn : INF;
  rb[t] = act ? sum : 0.f;
  if(t < 64){ ra[192+t] = INF; rb[192+t] = 0.f; }
  __syncthreads();
  for(int s=128; s>0; s>>=1){
    if(t < s){ ra[t]=fminf(ra[t],ra[t+s]); rb[t]+=rb[t+s]; }
    __syncthreads();
  }
  if(t==0){ sb[0]=ra[0]; sb[1]=0.3f*(rb[0]/(float)HW + 1e-6f); }
  __syncthreads();
  float base = sb[0], th = sb[1];
  float s = sgm(fsr[c]);

  __bf16* fp = fill16 + (size_t)bc*HW;
  float amax=0.f, asum=0.f;
  Mp=-INF; mp=INF;
  float cen;
  {
    float C0 = xp[lc];
    float Lv = __shfl_up(C0,1), Rv = __shfl_down(C0,1);
    Mc = fmaxf(fmaxf(Lv,C0),Rv); mc = fminf(fminf(Lv,C0),Rv);
    cen = C0;
  }
  load8s(xp, lc, 1, CA);
  for(int h0=0; h0<HH; h0+=16){
    load8s(xp, lc, h0+9, CB);
    proc2s(h0,   lc, act, CA, Mp, mp, Mc, mc, cen, amax, asum, th, base, s, fp);
    if(h0+16 < HH) load8s(xp, lc, h0+17, CA);
    proc2s(h0+8, lc, act, CB, Mp, mp, Mc, mc, cen, amax, asum, th, base, s, fp);
  }
  ra[t] = act ? amax : 0.f;
  rb[t] = act ? asum : 0.f;
  if(t < 64){ ra[192+t] = 0.f; rb[192+t] = 0.f; }
  __syncthreads();
  for(int st=128; st>0; st>>=1){
    if(t < st){ ra[t]=fmaxf(ra[t],ra[t+st]); rb[t]+=rb[t+st]; }
    __syncthreads();
  }
  if(t==0) chw[bc] = sgm(3.0f*(ra[0] - rb[0]/(float)HW - 0.3f));
}

// K3: xs[b,p] = mean_c |fill16|, bfv8 loads, 400x64 grid
__global__ __launch_bounds__(64) void k3_xs(const __bf16* __restrict__ fill16,
                                            float* __restrict__ xs){
  int i = blockIdx.x*64 + threadIdx.x;
  int b = i / (HW/8); int p8 = (i - b*(HW/8))*8;
  const __bf16* fp = fill16 + (size_t)b*CC*HW + p8;
  float s0=0,s1=0,s2=0,s3=0,s4=0,s5=0,s6=0,s7=0;
  #pragma unroll 4
  for(int c=0; c<CC; ++c){
    bfv8 v = *(const bfv8*)(fp + (size_t)c*HW);
    s0 += fabsf((float)v[0]); s1 += fabsf((float)v[1]);
    s2 += fabsf((float)v[2]); s3 += fabsf((float)v[3]);
    s4 += fabsf((float)v[4]); s5 += fabsf((float)v[5]);
    s6 += fabsf((float)v[6]); s7 += fabsf((float)v[7]);
  }
  f4 r0 = {s0*(1.f/CC), s1*(1.f/CC), s2*(1.f/CC), s3*(1.f/CC)};
  f4 r1 = {s4*(1.f/CC), s5*(1.f/CC), s6*(1.f/CC), s7*(1.f/CC)};
  *(f4*)(xs + (size_t)b*HW + p8)     = r0;
  *(f4*)(xs + (size_t)b*HW + p8 + 4) = r1;
}

// K4: ew[b,p] = sigmoid(5*(win3contrast(xs) - 0.5)); rolling 32-row strips.
// max/min exactly associative -> ew bitwise matches the old inline ewl.
__global__ __launch_bounds__(256) void k4_ew(const float* __restrict__ xs,
                                             float* __restrict__ ew){
  int b  = blockIdx.x / 5;
  int r0 = (blockIdx.x % 5) * 32;
  int w  = threadIdx.x;
  if(w >= WW) return;
  const float* xp = xs + (size_t)b*HW;
  float* ep = ew + (size_t)b*HW;
  float hMp, hmp, hMc, hmc, hMn, hmn;
  if(r0 > 0) hrow3L(xp + (r0-1)*WW, w, hMp, hmp); else { hMp=-INF; hmp=INF; }
  hrow3L(xp + r0*WW, w, hMc, hmc);
  #pragma unroll 4
  for(int h=r0; h<r0+32; ++h){
    if(h < HH-1) hrow3L(xp + (h+1)*WW, w, hMn, hmn); else { hMn=-INF; hmn=INF; }
    float contrast = fmaxf(fmaxf(hMp,hMc),hMn) - fminf(fminf(hmp,hmc),hmn);
    ep[h*WW + w] = sgm(5.0f*(contrast - 0.5f));
    hMp=hMc; hmp=hmc; hMc=hMn; hmc=hmn;
  }
}

// C1F: fused enhance + conv1. Stage gain-applied 64px x 128ic bf16 tile in
// LDS (math identical to old k_enh, ew read from buffer), MFMA from LDS.
__global__ __launch_bounds__(256) void c1f(const __bf16* __restrict__ fill16,
                                           const float* __restrict__ chw,
                                           const float* __restrict__ ew,
                                           const __bf16* __restrict__ w1b,
                                           const float* __restrict__ scsh,
                                           __bf16* __restrict__ o1p){
  __shared__ __bf16 tile[64][132];
  __shared__ float ewl[64];
  int b  = blockIdx.x / 400;
  int p0 = (blockIdx.x % 400) * 64;
  int t  = threadIdx.x;
  if(t < 64) ewl[t] = ew[(size_t)b*HW + p0 + t];
  __syncthreads();
  #pragma unroll
  for(int e=0; e<8; ++e){
    int idx = e*256 + t; int ic = idx >> 4; int pp = (idx & 15)*4;
    bfv4 v = *(const bfv4*)(fill16 + ((size_t)(b*CC + ic))*HW + p0 + pp);
    float g = chw[b*CC + ic];
    #pragma unroll
    for(int i2=0;i2<4;++i2)
      tile[pp+i2][ic] = (__bf16)((float)v[i2] * g * (1.f + ewl[pp+i2]));
  }
  int lane = t & 63, wv = t >> 6;
  int q = lane >> 4, j = lane & 15;
  bfv8 afr[4][4];
  #pragma unroll
  for(int mt=0; mt<4; ++mt)
    #pragma unroll
    for(int kk=0; kk<4; ++kk)
      afr[mt][kk] = *(const bfv8*)&w1b[(mt*16 + j)*CC + kk*32 + q*8];
  f4 sc4[4], sh4[4];
  #pragma unroll
  for(int mt=0; mt<4; ++mt){
    sc4[mt] = *(const f4*)&scsh[mt*16 + q*4];
    sh4[mt] = *(const f4*)&scsh[64 + mt*16 + q*4];
  }
  __syncthreads();
  bfv8 bf[4];
  #pragma unroll
  for(int kk=0; kk<4; ++kk) bf[kk] = *(const bfv8*)&tile[wv*16 + j][kk*32 + q*8];
  f4 acc[4] = {{0,0,0,0},{0,0,0,0},{0,0,0,0},{0,0,0,0}};
  #pragma unroll
  for(int kk=0; kk<4; ++kk)
    #pragma unroll
    for(int mt=0; mt<4; ++mt)
      acc[mt] = MFMA(afr[mt][kk], bf[kk], acc[mt]);
  int px = p0 + wv*16 + j;
  int h = px / WW; int w = px - h*WW;
  __bf16* op = o1p + (size_t)b*PP*PP*CH + ((size_t)(h+1)*PP + (w+1))*CH + q*4;
  #pragma unroll
  for(int mt=0; mt<4; ++mt){
    bfv4 ov;
    #pragma unroll
    for(int rr=0; rr<4; ++rr){
      float z = acc[mt][rr]*sc4[mt][rr] + sh4[mt][rr];
      ov[rr] = (__bf16)silu_(z);
    }
    *(bfv4*)(op + mt*16) = ov;
  }
}

// C2: o2 = silu(bn2(conv3x3(o1p))). LDS-shared swizzled input tile. (frozen)
__global__ __launch_bounds__(256) void c2_mfma(const __bf16* __restrict__ o1p,
                                               const __bf16* __restrict__ w2b,
                                               const float* __restrict__ scsh,
                                               __bf16* __restrict__ o2){
  __shared__ __bf16 lds[4*82*64];
  int lane = threadIdx.x & 63, mt = threadIdx.x >> 6;
  int u = blockIdx.x;
  int b = u / 160; int r_ = u % 160; int hp = r_ >> 1; int wh = r_ & 1;
  int h0 = hp*2;
  int wstart = wh*80;
  int q = lane >> 4, j = lane & 15;
  const __bf16* ibase = o1p + (size_t)b*PP*PP*CH;
  {
    int t = threadIdx.x;
    int wvbase = t & ~63;
    #pragma unroll
    for(int it=0; it<11; ++it){
      int i = it*256 + t;
      if(i < 2624){
        int r = i / 656; int rem = i - r*656;
        int w = rem >> 3; int kp = rem & 7;
        int k = kp ^ (w & 7);
        const __bf16* src = ibase + ((size_t)(h0+r)*PP + wstart + w)*CH + k*8;
        char* dst = (char*)lds + (size_t)(it*256 + wvbase)*16;
        __builtin_amdgcn_global_load_lds((const __attribute__((address_space(1))) void*)src,
                                         (__attribute__((address_space(3))) void*)dst,
                                         16, 0, 0);
      }
    }
  }
  bfv8 afr[9][2];
  #pragma unroll
  for(int t=0; t<9; ++t)
    #pragma unroll
    for(int icb=0; icb<2; ++icb)
      afr[t][icb] = *(const bfv8*)&w2b[(t*CH + mt*16 + j)*CH + icb*32 + q*8];
  f4 sc4 = *(const f4*)&scsh[128 + mt*16 + q*4];
  f4 sh4 = *(const f4*)&scsh[192 + mt*16 + q*4];
  asm volatile("s_waitcnt vmcnt(0)" ::: "memory");
  __syncthreads();

  __bf16* obase = o2 + (size_t)b*HW*CH;
  for(int s5=0; s5<5; ++s5){
    int wb = s5*16;
    f4 a00={0,0,0,0}, a01={0,0,0,0}, a10={0,0,0,0}, a11={0,0,0,0};
    #pragma unroll
    for(int r=0; r<4; ++r){
      bfv8 bv0[3], bv1[3];
      #pragma unroll
      for(int dw=0; dw<3; ++dw){
        int wl = wb + j + dw;
        int basee = r*5248 + wl*64;
        int k0 = q ^ (wl & 7);
        bv0[dw] = *(const bfv8*)&lds[basee + k0*8];
        bv1[dw] = *(const bfv8*)&lds[basee + (k0^4)*8];
      }
      #pragma unroll
      for(int dw=0; dw<3; ++dw){
        if(r < 3){
          a00 = MFMA(afr[r*3+dw][0], bv0[dw], a00);
          a01 = MFMA(afr[r*3+dw][1], bv1[dw], a01);
        }
        if(r >= 1){
          a10 = MFMA(afr[(r-1)*3+dw][0], bv0[dw], a10);
          a11 = MFMA(afr[(r-1)*3+dw][1], bv1[dw], a11);
        }
      }
    }
    f4 acc0 = a00 + a01, acc1 = a10 + a11;
    int w0 = wstart + wb;
    __bf16* op0 = obase + ((size_t)(h0*WW + w0 + j))*CH + mt*16 + q*4;
    __bf16* op1 = obase + ((size_t)((h0+1)*WW + w0 + j))*CH + mt*16 + q*4;
    bfv4 ov0, ov1;
    #pragma unroll
    for(int rr=0; rr<4; ++rr){
      ov0[rr] = (__bf16)silu_(acc0[rr]*sc4[rr] + sh4[rr]);
      ov1[rr] = (__bf16)silu_(acc1[rr]*sc4[rr] + sh4[rr]);
    }
    *(bfv4*)op0 = ov0;
    *(bfv4*)op1 = ov1;
  }
}

// C3: out = silu(bn3(w3 @ o2) + fill16*chw*(1+ew)); residual computed f32
// from NCHW fill16 in the post-transpose store loop (coalesced).
__global__ __launch_bounds__(256) void c3_mfma(const __bf16* __restrict__ o2,
                                               const __bf16* __restrict__ w3b,
                                               const float* __restrict__ scsh,
                                               const __bf16* __restrict__ fill16,
                                               const float* __restrict__ chw,
                                               const float* __restrict__ ew,
                                               float* __restrict__ out){
  __shared__ float ot[CC][66];
  __shared__ float ewl[64];
  int lane = threadIdx.x & 63, wv = threadIdx.x >> 6;
  int b = blockIdx.x / 400; int p0 = (blockIdx.x % 400)*64;
  int q = lane >> 4, j = lane & 15;
  int t = threadIdx.x;
  if(t < 64) ewl[t] = ew[(size_t)b*HW + p0 + t];
  int px0 = wv*16;
  int pix = p0 + px0 + j;
  const __bf16* bp = o2 + ((size_t)b*HW + pix)*CH + q*8;
  bfv8 bf0 = *(const bfv8*)bp;
  bfv8 bf1 = *(const bfv8*)(bp + 32);
  f4 acc[8];
  #pragma unroll
  for(int mt=0; mt<8; ++mt){
    bfv8 a0 = *(const bfv8*)&w3b[(mt*16 + j)*CH + q*8];
    bfv8 a1 = *(const bfv8*)&w3b[(mt*16 + j)*CH + 32 + q*8];
    f4 z = {0.f,0.f,0.f,0.f};
    z = MFMA(a0, bf0, z);
    z = MFMA(a1, bf1, z);
    acc[mt] = z;
  }
  #pragma unroll
  for(int mt=0; mt<8; ++mt){
    f4 scg = *(const f4*)&scsh[256 + mt*16 + q*4];
    f4 shg = *(const f4*)&scsh[384 + mt*16 + q*4];
    #pragma unroll
    for(int rr=0; rr<4; ++rr)
      ot[mt*16 + q*4 + rr][px0 + j] = acc[mt][rr]*scg[rr] + shg[rr];  // pre-residual, pre-silu
  }
  __syncthreads();
  #pragma unroll
  for(int e=0; e<8; ++e){
    int oc = e*16 + (t >> 4);
    int c4 = (t & 15)*4;
    float cw = chw[b*CC + oc];
    bfv4 fb = *(const bfv4*)(fill16 + ((size_t)(b*CC + oc))*HW + p0 + c4);
    f4 v = *(const f4*)&ot[oc][c4];
    f4 r;
    #pragma unroll
    for(int i2=0;i2<4;++i2){
      float res = (float)fb[i2] * cw * (1.f + ewl[c4+i2]);
      r[i2] = silu_(v[i2] + res);
    }
    *(f4*)&out[((size_t)(b*CC + oc))*HW + p0 + c4] = r;
  }
}

extern "C" void kernel_launch(void* const* d_in, const int* in_sizes, int n_in,
                              void* d_out, int out_size, void* d_ws, size_t ws_size,
                              hipStream_t stream) {
  const float* x   = (const float*)d_in[0];
  const float* fsr = (const float*)d_in[1];
  const float* w1  = (const float*)d_in[2];
  const float* g1  = (const float*)d_in[3];
  const float* b1  = (const float*)d_in[4];
  const float* m1  = (const float*)d_in[5];
  const float* v1  = (const float*)d_in[6];
  const float* w2  = (const float*)d_in[7];
  const float* g2  = (const float*)d_in[8];
  const float* b2  = (const float*)d_in[9];
  const float* m2  = (const float*)d_in[10];
  const float* v2  = (const float*)d_in[11];
  const float* w3  = (const float*)d_in[12];
  const float* g3  = (const float*)d_in[13];
  const float* b3  = (const float*)d_in[14];
  const float* m3  = (const float*)d_in[15];
  const float* v3  = (const float*)d_in[16];
  float* out = (float*)d_out;

  char* wp = (char*)d_ws;
  __bf16* fill16 = (__bf16*)wp;  wp += (size_t)BB*CC*HW*2;       // 52.4 MB
  __bf16* o1p    = (__bf16*)wp;  wp += (size_t)BB*PP*PP*CH*2;    // 26.9 MB
  __bf16* o2b    = (__bf16*)wp;  wp += (size_t)BB*HW*CH*2;       // 26.2 MB
  float*  xs     = (float*)wp;   wp += (size_t)BB*HW*4;
  float*  ewb    = (float*)wp;   wp += (size_t)BB*HW*4;
  float*  chw    = (float*)wp;   wp += 1024*4;
  __bf16* w1b    = (__bf16*)wp;  wp += (size_t)CH*CC*2;
  __bf16* w3b    = (__bf16*)wp;  wp += (size_t)CC*CH*2;
  __bf16* w2b    = (__bf16*)wp;  wp += (size_t)9*CH*CH*2;
  float*  scsh   = (float*)wp;   wp += 512*4;

  kprep2  <<<dim3(72), dim3(256), 0, stream>>>(w1,g1,b1,m1,v1, w2,g2,b2,m2,v2,
                                               w3,g3,b3,m3,v3, w1b,w2b,w3b,scsh, o1p);
  k12     <<<dim3(BB*CC), dim3(192), 0, stream>>>(x, fsr, fill16, chw);
  k3_xs   <<<dim3(400), dim3(64), 0, stream>>>(fill16, xs);
  k4_ew   <<<dim3(BB*5), dim3(256), 0, stream>>>(xs, ewb);
  c1f     <<<dim3(BB*400), dim3(256), 0, stream>>>(fill16, chw, ewb, w1b, scsh, o1p);
  c2_mfma <<<dim3(1280), dim3(256), 0, stream>>>(o1p, w2b, scsh, o2b);
  c3_mfma <<<dim3(3200), dim3(256), 0, stream>>>(o2b, w3b, scsh, fill16, chw, ewb, out);
}

// Round 17
// 192.010 us; speedup vs baseline: 1.0822x; 1.0822x over previous
//
#include <hip/hip_runtime.h>
#include <math.h>

#define BB 8
#define CC 128
#define CH 64
#define HH 160
#define WW 160
#define HW (HH*WW)
#define PP 162            // padded width/height for conv2 input
#define INF __builtin_inff()

typedef __bf16 bfv8 __attribute__((ext_vector_type(8)));
typedef __bf16 bfv4 __attribute__((ext_vector_type(4)));
typedef float  f4   __attribute__((ext_vector_type(4)));

__device__ __forceinline__ float sgm(float z){ return 1.0f/(1.0f + __expf(-z)); }
__device__ __forceinline__ float silu_(float z){ return z/(1.0f + __expf(-z)); }
__device__ __forceinline__ f4 MFMA(bfv8 a, bfv8 b, f4 c){
  return __builtin_amdgcn_mfma_f32_16x16x32_bf16(a, b, c, 0, 0, 0);
}

// KPREP2: blocks 0-63 = weight prep (bf16 + folded BN); blocks 64-71 = border zero
__global__ __launch_bounds__(256) void kprep2(const float* __restrict__ w1,
                                              const float* __restrict__ g1, const float* __restrict__ b1,
                                              const float* __restrict__ m1, const float* __restrict__ v1,
                                              const float* __restrict__ w2,
                                              const float* __restrict__ g2, const float* __restrict__ b2,
                                              const float* __restrict__ m2, const float* __restrict__ v2,
                                              const float* __restrict__ w3,
                                              const float* __restrict__ g3, const float* __restrict__ b3,
                                              const float* __restrict__ m3, const float* __restrict__ v3,
                                              __bf16* __restrict__ w1b, __bf16* __restrict__ w2b,
                                              __bf16* __restrict__ w3b, float* __restrict__ scsh,
                                              __bf16* __restrict__ o1p){
  int bid = blockIdx.x;
  if(bid < 64){
    int t = bid*256 + threadIdx.x;
    int stride = 64*256;
    for(int i=t; i<CH*CC; i+=stride) w1b[i] = (__bf16)w1[i];
    for(int i=t; i<CC*CH; i+=stride) w3b[i] = (__bf16)w3[i];
    for(int i=t; i<9*CH*CH; i+=stride){
      int tap = i >> 12; int rem = i & 4095; int oc = rem >> 6; int ic = rem & 63;
      w2b[i] = (__bf16)w2[(oc*CH + ic)*9 + tap];
    }
    if(t < CH){
      float s = g1[t]*rsqrtf(v1[t] + 1e-5f);
      scsh[t] = s; scsh[64+t] = b1[t] - m1[t]*s;
      float s2 = g2[t]*rsqrtf(v2[t] + 1e-5f);
      scsh[128+t] = s2; scsh[192+t] = b2[t] - m2[t]*s2;
    }
    if(t >= 64 && t < 64+CC){
      int c = t - 64;
      float s3 = g3[c]*rsqrtf(v3[c] + 1e-5f);
      scsh[256+c] = s3; scsh[384+c] = b3[c] - m3[c]*s3;
    }
  } else {
    int b = bid - 64;
    __bf16* base = o1p + (size_t)b*PP*PP*CH;
    int t = threadIdx.x;
    bfv4 z = {(__bf16)0.f,(__bf16)0.f,(__bf16)0.f,(__bf16)0.f};
    for(int i=t; i<644*16; i+=256){
      int e = i >> 4; int c4 = (i & 15)*4;
      int h, w;
      if(e < 162){ h = 0; w = e; }
      else if(e < 324){ h = 161; w = e - 162; }
      else if(e < 484){ h = e - 324 + 1; w = 0; }
      else { h = e - 484 + 1; w = 161; }
      *(bfv4*)(base + ((size_t)h*PP + w)*CH + c4) = z;
    }
  }
}

// ---- k12 helpers: single C stream, halo via intra-wave shuffle ----
__device__ __forceinline__ void load8s(const float* __restrict__ xp, int lc,
                                       int start, float (&C)[8]){
  #pragma unroll
  for(int k=0;k<8;++k){
    int hr = start + k;
    C[k] = (hr < HH) ? xp[hr*WW + lc] : 0.f;
  }
}

// NOTE: contains __shfl — must be executed by ALL lanes (no divergence).
__device__ __forceinline__ void proc1s(int base, const float (&C)[8],
                                       float& Mp, float& mp, float& Mc, float& mc,
                                       float& mn, float& sum){
  #pragma unroll
  for(int k=0;k<8;++k){
    int hr = base + 1 + k;
    float Lv = __shfl_up(C[k],1), Rv = __shfl_down(C[k],1);
    float Mn, mr;
    if(hr < HH){                              // wave-uniform condition
      Mn = fmaxf(fmaxf(Lv,C[k]),Rv);
      mr = fminf(fminf(Lv,C[k]),Rv);
      mn = fminf(mn, C[k]);
    } else { Mn = -INF; mr = INF; }
    sum += fmaxf(fmaxf(Mp,Mc),Mn) - fminf(fminf(mp,mc),mr);
    Mp=Mc; mp=mc; Mc=Mn; mc=mr;
  }
}

__device__ __forceinline__ void proc2s(int base, int lc, bool act, const float (&C)[8],
                                       float& Mp, float& mp, float& Mc, float& mc,
                                       float& cen, float& amax, float& asum,
                                       float th, float basev, float s,
                                       __bf16* __restrict__ fp){
  #pragma unroll
  for(int k=0;k<8;++k){
    int hr = base + 1 + k;
    int h  = base + k;
    float Lv = __shfl_up(C[k],1), Rv = __shfl_down(C[k],1);
    float Mn, mr;
    if(hr < HH){
      Mn = fmaxf(fmaxf(Lv,C[k]),Rv);
      mr = fminf(fminf(Lv,C[k]),Rv);
    } else { Mn = -INF; mr = INF; }
    float contrast = fmaxf(fmaxf(Mp,Mc),Mn) - fminf(fminf(mp,mc),mr);
    float f = (contrast < th) ? cen*(1.f-s) + basev*s : cen;
    if(act) fp[h*WW + lc] = (__bf16)f;
    float a = fabsf(f);
    amax = fmaxf(amax, a); asum += a;
    Mp=Mc; mp=mc; Mc=Mn; mc=mr; cen = C[k];
  }
}

// K12: fused stats + fill (bf16 out). 192 threads = 3 waves; wave w loads 64
// clamped columns lc=62w+l-1, outputs the middle 62 (lanes 1..62). Halo via
// __shfl of the single C stream. (R14 passing version, frozen.)
__global__ __launch_bounds__(192) void k12(const float* __restrict__ x,
                                           const float* __restrict__ fsr,
                                           __bf16* __restrict__ fill16,
                                           float* __restrict__ chw){
  __shared__ float ra[256], rb[256];
  __shared__ float sb[2];
  int bc = blockIdx.x;
  int c  = bc & (CC-1);
  int t  = threadIdx.x;
  int w  = t >> 6, l = t & 63;
  int oc = 62*w + l - 1;
  bool act = (l >= 1) && (l <= 62) && (oc < WW);
  int lc = oc < 0 ? 0 : (oc > WW-1 ? WW-1 : oc);   // clamped load column
  const float* xp = x + (size_t)bc*HW;

  float CA[8], CB[8];

  // ---- pass 1 ----
  float mn = INF, sum = 0.f;
  float Mp=-INF, mp=INF, Mc, mc;
  {
    float C0 = xp[lc];
    float Lv = __shfl_up(C0,1), Rv = __shfl_down(C0,1);
    Mc = fmaxf(fmaxf(Lv,C0),Rv); mc = fminf(fminf(Lv,C0),Rv);
    mn = C0;
  }
  load8s(xp, lc, 1, CA);
  for(int h0=0; h0<HH; h0+=16){
    load8s(xp, lc, h0+9, CB);
    proc1s(h0,   CA, Mp, mp, Mc, mc, mn, sum);
    if(h0+16 < HH) load8s(xp, lc, h0+17, CA);
    proc1s(h0+8, CB, Mp, mp, Mc, mc, mn, sum);
  }
  ra[t] = act ? mn : INF;
  rb[t] = act ? sum : 0.f;
  if(t < 64){ ra[192+t] = INF; rb[192+t] = 0.f; }
  __syncthreads();
  for(int s=128; s>0; s>>=1){
    if(t < s){ ra[t]=fminf(ra[t],ra[t+s]); rb[t]+=rb[t+s]; }
    __syncthreads();
  }
  if(t==0){ sb[0]=ra[0]; sb[1]=0.3f*(rb[0]/(float)HW + 1e-6f); }
  __syncthreads();
  float base = sb[0], th = sb[1];
  float s = sgm(fsr[c]);

  // ---- pass 2 ----
  __bf16* fp = fill16 + (size_t)bc*HW;
  float amax=0.f, asum=0.f;
  Mp=-INF; mp=INF;
  float cen;
  {
    float C0 = xp[lc];
    float Lv = __shfl_up(C0,1), Rv = __shfl_down(C0,1);
    Mc = fmaxf(fmaxf(Lv,C0),Rv); mc = fminf(fminf(Lv,C0),Rv);
    cen = C0;
  }
  load8s(xp, lc, 1, CA);
  for(int h0=0; h0<HH; h0+=16){
    load8s(xp, lc, h0+9, CB);
    proc2s(h0,   lc, act, CA, Mp, mp, Mc, mc, cen, amax, asum, th, base, s, fp);
    if(h0+16 < HH) load8s(xp, lc, h0+17, CA);
    proc2s(h0+8, lc, act, CB, Mp, mp, Mc, mc, cen, amax, asum, th, base, s, fp);
  }
  ra[t] = act ? amax : 0.f;
  rb[t] = act ? asum : 0.f;
  if(t < 64){ ra[192+t] = 0.f; rb[192+t] = 0.f; }
  __syncthreads();
  for(int st=128; st>0; st>>=1){
    if(t < st){ ra[t]=fmaxf(ra[t],ra[t+st]); rb[t]+=rb[t+st]; }
    __syncthreads();
  }
  if(t==0) chw[bc] = sgm(3.0f*(ra[0] - rb[0]/(float)HW - 0.3f));
}

// K3: xs[b,p] = mean_c |fill16|, bfv8 loads. 64-thread blocks x 400 grid.
__global__ __launch_bounds__(64) void k3_xs(const __bf16* __restrict__ fill16,
                                            float* __restrict__ xs){
  int i = blockIdx.x*64 + threadIdx.x;
  int b = i / (HW/8); int p8 = (i - b*(HW/8))*8;
  const __bf16* fp = fill16 + (size_t)b*CC*HW + p8;
  float s0=0,s1=0,s2=0,s3=0,s4=0,s5=0,s6=0,s7=0;
  #pragma unroll 4
  for(int c=0; c<CC; ++c){
    bfv8 v = *(const bfv8*)(fp + (size_t)c*HW);
    s0 += fabsf((float)v[0]); s1 += fabsf((float)v[1]);
    s2 += fabsf((float)v[2]); s3 += fabsf((float)v[3]);
    s4 += fabsf((float)v[4]); s5 += fabsf((float)v[5]);
    s6 += fabsf((float)v[6]); s7 += fabsf((float)v[7]);
  }
  f4 r0 = {s0*(1.f/CC), s1*(1.f/CC), s2*(1.f/CC), s3*(1.f/CC)};
  f4 r1 = {s4*(1.f/CC), s5*(1.f/CC), s6*(1.f/CC), s7*(1.f/CC)};
  *(f4*)(xs + (size_t)b*HW + p8)     = r0;
  *(f4*)(xs + (size_t)b*HW + p8 + 4) = r1;
}

// K_ENH: enh[b][p][ic] (NHWC bf16) = fill16 * chw * (1+ew), ew inline from xs.
// bfv4 (8B/lane) global loads.
__global__ __launch_bounds__(256) void k_enh(const __bf16* __restrict__ fill16,
                                             const float* __restrict__ chw,
                                             const float* __restrict__ xs,
                                             __bf16* __restrict__ enh){
  __shared__ __bf16 tile[64][132];
  __shared__ float ewl[64];
  int b  = blockIdx.x / 400;
  int p0 = (blockIdx.x % 400) * 64;
  int t  = threadIdx.x;
  if(t < 64){
    int p = p0 + t; int h = p/WW, w = p - h*WW;
    const float* xpb = xs + (size_t)b*HW;
    int h0 = h>0?h-1:0, h1 = h<HH-1?h+1:h;
    int w0 = w>0?w-1:0, w1 = w<WW-1?w+1:w;
    float M = -INF, m = INF;
    for(int hh=h0; hh<=h1; ++hh)
      for(int ww=w0; ww<=w1; ++ww){
        float v = xpb[hh*WW+ww]; M = fmaxf(M,v); m = fminf(m,v);
      }
    ewl[t] = sgm(5.0f*((M-m) - 0.5f));
  }
  __syncthreads();
  #pragma unroll
  for(int e=0; e<8; ++e){
    int idx = e*256 + t; int ic = idx >> 4; int pp = (idx & 15)*4;
    bfv4 v = *(const bfv4*)(fill16 + ((size_t)(b*CC + ic))*HW + p0 + pp);
    float g = chw[b*CC + ic];
    #pragma unroll
    for(int i2=0;i2<4;++i2)
      tile[pp+i2][ic] = (__bf16)((float)v[i2] * g * (1.f + ewl[pp+i2]));
  }
  __syncthreads();
  #pragma unroll
  for(int e=0; e<8; ++e){
    int idx = e*256 + t; int p = idx >> 5; int icg = idx & 31;
    bfv4 v = *(const bfv4*)&tile[p][icg*4];
    *(bfv4*)&enh[((size_t)(b*HW + p0 + p))*CC + icg*4] = v;
  }
}

// C1: o1p(padded NHWC bf16) = silu(bn1(w1 @ enh))
__global__ __launch_bounds__(256) void c1_mfma(const __bf16* __restrict__ enh,
                                               const __bf16* __restrict__ w1b,
                                               const float* __restrict__ scsh,
                                               __bf16* __restrict__ o1p){
  int lane = threadIdx.x & 63, wv = threadIdx.x >> 6;
  int u = blockIdx.x*4 + wv;            // 2560 units: b(8) x h(160) x half(2)
  int b = u / 320; int r = u % 320; int h = r >> 1; int w0base = (r & 1)*80;
  int q = lane >> 4, j = lane & 15;
  bfv8 afr[4][4];
  #pragma unroll
  for(int mt=0; mt<4; ++mt)
    #pragma unroll
    for(int kk=0; kk<4; ++kk)
      afr[mt][kk] = *(const bfv8*)&w1b[(mt*16 + j)*CC + kk*32 + q*8];
  f4 sc4[4], sh4[4];
  #pragma unroll
  for(int mt=0; mt<4; ++mt){
    sc4[mt] = *(const f4*)&scsh[mt*16 + q*4];
    sh4[mt] = *(const f4*)&scsh[64 + mt*16 + q*4];
  }
  const __bf16* ebase = enh + (size_t)b*HW*CC;
  __bf16* obase = o1p + (size_t)b*PP*PP*CH;
  for(int s5=0; s5<5; ++s5){
    int w0 = w0base + s5*16;
    int p0 = h*WW + w0;
    const __bf16* bp = ebase + (size_t)(p0 + j)*CC + q*8;
    bfv8 bf[4];
    #pragma unroll
    for(int kk=0; kk<4; ++kk) bf[kk] = *(const bfv8*)(bp + kk*32);
    f4 acc[4] = {{0,0,0,0},{0,0,0,0},{0,0,0,0},{0,0,0,0}};
    #pragma unroll
    for(int kk=0; kk<4; ++kk)
      #pragma unroll
      for(int mt=0; mt<4; ++mt)
        acc[mt] = MFMA(afr[mt][kk], bf[kk], acc[mt]);
    int w = w0 + j;
    __bf16* op = obase + ((size_t)(h+1)*PP + (w+1))*CH + q*4;
    #pragma unroll
    for(int mt=0; mt<4; ++mt){
      bfv4 ov;
      #pragma unroll
      for(int rr=0; rr<4; ++rr){
        float z = acc[mt][rr]*sc4[mt][rr] + sh4[mt][rr];
        ov[rr] = (__bf16)silu_(z);
      }
      *(bfv4*)(op + mt*16) = ov;
    }
  }
}

// C2: o2 = silu(bn2(conv3x3(o1p))). LDS-shared swizzled input tile.
__global__ __launch_bounds__(256) void c2_mfma(const __bf16* __restrict__ o1p,
                                               const __bf16* __restrict__ w2b,
                                               const float* __restrict__ scsh,
                                               __bf16* __restrict__ o2){
  __shared__ __bf16 lds[4*82*64];
  int lane = threadIdx.x & 63, mt = threadIdx.x >> 6;
  int u = blockIdx.x;
  int b = u / 160; int r_ = u % 160; int hp = r_ >> 1; int wh = r_ & 1;
  int h0 = hp*2;
  int wstart = wh*80;
  int q = lane >> 4, j = lane & 15;
  const __bf16* ibase = o1p + (size_t)b*PP*PP*CH;
  {
    int t = threadIdx.x;
    int wvbase = t & ~63;
    #pragma unroll
    for(int it=0; it<11; ++it){
      int i = it*256 + t;
      if(i < 2624){
        int r = i / 656; int rem = i - r*656;
        int w = rem >> 3; int kp = rem & 7;
        int k = kp ^ (w & 7);
        const __bf16* src = ibase + ((size_t)(h0+r)*PP + wstart + w)*CH + k*8;
        char* dst = (char*)lds + (size_t)(it*256 + wvbase)*16;
        __builtin_amdgcn_global_load_lds((const __attribute__((address_space(1))) void*)src,
                                         (__attribute__((address_space(3))) void*)dst,
                                         16, 0, 0);
      }
    }
  }
  bfv8 afr[9][2];
  #pragma unroll
  for(int t=0; t<9; ++t)
    #pragma unroll
    for(int icb=0; icb<2; ++icb)
      afr[t][icb] = *(const bfv8*)&w2b[(t*CH + mt*16 + j)*CH + icb*32 + q*8];
  f4 sc4 = *(const f4*)&scsh[128 + mt*16 + q*4];
  f4 sh4 = *(const f4*)&scsh[192 + mt*16 + q*4];
  asm volatile("s_waitcnt vmcnt(0)" ::: "memory");
  __syncthreads();

  __bf16* obase = o2 + (size_t)b*HW*CH;
  for(int s5=0; s5<5; ++s5){
    int wb = s5*16;
    f4 a00={0,0,0,0}, a01={0,0,0,0}, a10={0,0,0,0}, a11={0,0,0,0};
    #pragma unroll
    for(int r=0; r<4; ++r){
      bfv8 bv0[3], bv1[3];
      #pragma unroll
      for(int dw=0; dw<3; ++dw){
        int wl = wb + j + dw;
        int basee = r*5248 + wl*64;
        int k0 = q ^ (wl & 7);
        bv0[dw] = *(const bfv8*)&lds[basee + k0*8];
        bv1[dw] = *(const bfv8*)&lds[basee + (k0^4)*8];
      }
      #pragma unroll
      for(int dw=0; dw<3; ++dw){
        if(r < 3){
          a00 = MFMA(afr[r*3+dw][0], bv0[dw], a00);
          a01 = MFMA(afr[r*3+dw][1], bv1[dw], a01);
        }
        if(r >= 1){
          a10 = MFMA(afr[(r-1)*3+dw][0], bv0[dw], a10);
          a11 = MFMA(afr[(r-1)*3+dw][1], bv1[dw], a11);
        }
      }
    }
    f4 acc0 = a00 + a01, acc1 = a10 + a11;
    int w0 = wstart + wb;
    __bf16* op0 = obase + ((size_t)(h0*WW + w0 + j))*CH + mt*16 + q*4;
    __bf16* op1 = obase + ((size_t)((h0+1)*WW + w0 + j))*CH + mt*16 + q*4;
    bfv4 ov0, ov1;
    #pragma unroll
    for(int rr=0; rr<4; ++rr){
      ov0[rr] = (__bf16)silu_(acc0[rr]*sc4[rr] + sh4[rr]);
      ov1[rr] = (__bf16)silu_(acc1[rr]*sc4[rr] + sh4[rr]);
    }
    *(bfv4*)op0 = ov0;
    *(bfv4*)op1 = ov1;
  }
}

// C3: out(NCHW f32) = silu(bn3(w3 @ o2) + enh), LDS-transposed coalesced store
__global__ __launch_bounds__(256) void c3_mfma(const __bf16* __restrict__ o2,
                                               const __bf16* __restrict__ w3b,
                                               const float* __restrict__ scsh,
                                               const __bf16* __restrict__ enh,
                                               float* __restrict__ out){
  __shared__ float ot[CC][66];
  int lane = threadIdx.x & 63, wv = threadIdx.x >> 6;
  int b = blockIdx.x / 400; int p0 = (blockIdx.x % 400)*64;
  int q = lane >> 4, j = lane & 15;
  int px0 = wv*16;
  int pix = p0 + px0 + j;
  const __bf16* bp = o2 + ((size_t)b*HW + pix)*CH + q*8;
  bfv8 bf0 = *(const bfv8*)bp;
  bfv8 bf1 = *(const bfv8*)(bp + 32);
  f4 acc[8];
  #pragma unroll
  for(int mt=0; mt<8; ++mt){
    bfv8 a0 = *(const bfv8*)&w3b[(mt*16 + j)*CH + q*8];
    bfv8 a1 = *(const bfv8*)&w3b[(mt*16 + j)*CH + 32 + q*8];
    f4 z = {0.f,0.f,0.f,0.f};
    z = MFMA(a0, bf0, z);
    z = MFMA(a1, bf1, z);
    acc[mt] = z;
  }
  const __bf16* ep = enh + ((size_t)b*HW + pix)*CC;
  #pragma unroll
  for(int mt=0; mt<8; ++mt){
    f4 scg = *(const f4*)&scsh[256 + mt*16 + q*4];
    f4 shg = *(const f4*)&scsh[384 + mt*16 + q*4];
    bfv4 e4 = *(const bfv4*)(ep + mt*16 + q*4);
    #pragma unroll
    for(int rr=0; rr<4; ++rr){
      float z = acc[mt][rr]*scg[rr] + shg[rr] + (float)e4[rr];
      ot[mt*16 + q*4 + rr][px0 + j] = silu_(z);
    }
  }
  __syncthreads();
  int t = threadIdx.x;
  #pragma unroll
  for(int e=0; e<8; ++e){
    int oc = e*16 + (t >> 4);
    int c4 = (t & 15)*4;
    f4 v = *(const f4*)&ot[oc][c4];
    *(f4*)&out[((size_t)(b*CC + oc))*HW + p0 + c4] = v;
  }
}

extern "C" void kernel_launch(void* const* d_in, const int* in_sizes, int n_in,
                              void* d_out, int out_size, void* d_ws, size_t ws_size,
                              hipStream_t stream) {
  const float* x   = (const float*)d_in[0];
  const float* fsr = (const float*)d_in[1];
  const float* w1  = (const float*)d_in[2];
  const float* g1  = (const float*)d_in[3];
  const float* b1  = (const float*)d_in[4];
  const float* m1  = (const float*)d_in[5];
  const float* v1  = (const float*)d_in[6];
  const float* w2  = (const float*)d_in[7];
  const float* g2  = (const float*)d_in[8];
  const float* b2  = (const float*)d_in[9];
  const float* m2  = (const float*)d_in[10];
  const float* v2  = (const float*)d_in[11];
  const float* w3  = (const float*)d_in[12];
  const float* g3  = (const float*)d_in[13];
  const float* b3  = (const float*)d_in[14];
  const float* m3  = (const float*)d_in[15];
  const float* v3  = (const float*)d_in[16];
  float* out = (float*)d_out;

  char* wp = (char*)d_ws;
  __bf16* fill16 = (__bf16*)wp;  wp += (size_t)BB*CC*HW*2;       // 52.4 MB
  __bf16* enh    = (__bf16*)wp;  wp += (size_t)BB*HW*CC*2;       // 52.4 MB
  __bf16* o1p    = (__bf16*)wp;  wp += (size_t)BB*PP*PP*CH*2;    // 26.9 MB
  __bf16* o2b    = (__bf16*)wp;  wp += (size_t)BB*HW*CH*2;       // 26.2 MB
  float*  xs     = (float*)wp;   wp += (size_t)BB*HW*4;
  float*  chw    = (float*)wp;   wp += 1024*4;
  __bf16* w1b    = (__bf16*)wp;  wp += (size_t)CH*CC*2;
  __bf16* w3b    = (__bf16*)wp;  wp += (size_t)CC*CH*2;
  __bf16* w2b    = (__bf16*)wp;  wp += (size_t)9*CH*CH*2;
  float*  scsh   = (float*)wp;   wp += 512*4;

  kprep2  <<<dim3(72), dim3(256), 0, stream>>>(w1,g1,b1,m1,v1, w2,g2,b2,m2,v2,
                                               w3,g3,b3,m3,v3, w1b,w2b,w3b,scsh, o1p);
  k12     <<<dim3(BB*CC), dim3(192), 0, stream>>>(x, fsr, fill16, chw);
  k3_xs   <<<dim3(400), dim3(64), 0, stream>>>(fill16, xs);
  k_enh   <<<dim3(BB*400), dim3(256), 0, stream>>>(fill16, chw, xs, enh);
  c1_mfma <<<dim3(640), dim3(256), 0, stream>>>(enh, w1b, scsh, o1p);
  c2_mfma <<<dim3(1280), dim3(256), 0, stream>>>(o1p, w2b, scsh, o2b);
  c3_mfma <<<dim3(3200), dim3(256), 0, stream>>>(o2b, w3b, scsh, enh, out);
}